// Round 1
// baseline (369.305 us; speedup 1.0000x reference)
//
#include <hip/hip_runtime.h>
#include <stdint.h>
#include <stddef.h>

#define DEV __device__ __forceinline__

typedef _Float16 f16x8 __attribute__((ext_vector_type(8)));
typedef float    f32x4 __attribute__((ext_vector_type(4)));
typedef int      i32x4 __attribute__((ext_vector_type(4)));

#define K2E 1.44269504088896340736f

DEV uint16_t f2h(float f) {
  _Float16 h = (_Float16)f;
  return __builtin_bit_cast(uint16_t, h);
}
DEV float h2f(uint16_t u) {
  return (float)__builtin_bit_cast(_Float16, u);
}
DEV f16x8 ldfrag(const uint16_t* p) {
  i32x4 v = *(const i32x4*)p;
  return __builtin_bit_cast(f16x8, v);
}
DEV f32x4 mfma16(f16x8 a, f16x8 b, f32x4 c) {
  return __builtin_amdgcn_mfma_f32_16x16x32_f16(a, b, c, 0, 0, 0);
}

union U16x8 { uint16_t u[8]; i32x4 v; };

// ---------------- cast f32 -> f16 (8 elems/thread) ----------------
__global__ __launch_bounds__(256) void cast_f16_kernel(
    const float* __restrict__ in, uint16_t* __restrict__ outp, int n8) {
  int i = blockIdx.x * 256 + threadIdx.x;
  if (i >= n8) return;
  float4 a = *(const float4*)(in + (size_t)i * 8);
  float4 b = *(const float4*)(in + (size_t)i * 8 + 4);
  U16x8 r;
  r.u[0] = f2h(a.x); r.u[1] = f2h(a.y); r.u[2] = f2h(a.z); r.u[3] = f2h(a.w);
  r.u[4] = f2h(b.x); r.u[5] = f2h(b.y); r.u[6] = f2h(b.z); r.u[7] = f2h(b.w);
  *(i32x4*)(outp + (size_t)i * 8) = r.v;
}

// ---------------- transpose + cast: W[1024][ldw] f32 -> Wt[n][1024] f16 ----
__global__ __launch_bounds__(256) void transpose_cast_kernel(
    const float* __restrict__ W, uint16_t* __restrict__ Wt, int ldw) {
  __shared__ float tile[64][65];
  int k0 = blockIdx.x * 64;
  int n0 = blockIdx.y * 64;
  int tid = threadIdx.x;
#pragma unroll
  for (int i = 0; i < 16; ++i) {
    int flat = i * 256 + tid;
    int r = flat >> 6, c = flat & 63;
    tile[r][c] = W[(size_t)(k0 + r) * ldw + n0 + c];
  }
  __syncthreads();
#pragma unroll
  for (int i = 0; i < 16; ++i) {
    int flat = i * 256 + tid;
    int r = flat >> 6, c = flat & 63;
    Wt[(size_t)(n0 + r) * 1024 + k0 + c] = f2h(tile[c][r]);
  }
}

// ---------------- GEMM: C[M,N] = A[M,K] @ Bt[N,K]^T  (f16 in, f32 out) -----
// 128x128 tile, BK=64, padded LDS (stride 72 halves) => conflict-free b128.
__global__ __launch_bounds__(256, 2) void gemm_bt_kernel(
    const uint16_t* __restrict__ A, const uint16_t* __restrict__ Bt,
    float* __restrict__ C, int N, int K, float scale) {
  __shared__ __align__(16) uint16_t As[128 * 72];
  __shared__ __align__(16) uint16_t Bs[128 * 72];
  int tid = threadIdx.x;
  int w = tid >> 6, lane = tid & 63, quad = lane >> 4, l15 = lane & 15;
  int wm = (w >> 1) * 64, wn = (w & 1) * 64;
  int bm = blockIdx.x, bn = blockIdx.y;
  const uint16_t* Arow = A + (size_t)(bm * 128) * K;
  const uint16_t* Brow = Bt + (size_t)(bn * 128) * K;
  f32x4 acc[4][4];
  f32x4 zero = {0.f, 0.f, 0.f, 0.f};
#pragma unroll
  for (int i = 0; i < 4; ++i)
#pragma unroll
    for (int j = 0; j < 4; ++j) acc[i][j] = zero;
  int ss = lane & 7;
  for (int k0 = 0; k0 < K; k0 += 64) {
    __syncthreads();
#pragma unroll
    for (int t = 0; t < 4; ++t) {
      int r = w * 32 + t * 8 + (lane >> 3);
      i32x4 va = *(const i32x4*)(Arow + (size_t)r * K + k0 + ss * 8);
      i32x4 vb = *(const i32x4*)(Brow + (size_t)r * K + k0 + ss * 8);
      *(i32x4*)(As + r * 72 + ss * 8) = va;
      *(i32x4*)(Bs + r * 72 + ss * 8) = vb;
    }
    __syncthreads();
#pragma unroll
    for (int ks = 0; ks < 2; ++ks) {
      f16x8 af[4], bf[4];
#pragma unroll
      for (int mt = 0; mt < 4; ++mt)
        af[mt] = ldfrag(As + (wm + mt * 16 + l15) * 72 + ks * 32 + quad * 8);
#pragma unroll
      for (int nt = 0; nt < 4; ++nt)
        bf[nt] = ldfrag(Bs + (wn + nt * 16 + l15) * 72 + ks * 32 + quad * 8);
#pragma unroll
      for (int mt = 0; mt < 4; ++mt)
#pragma unroll
        for (int nt = 0; nt < 4; ++nt)
          acc[mt][nt] = mfma16(af[mt], bf[nt], acc[mt][nt]);
    }
  }
#pragma unroll
  for (int mt = 0; mt < 4; ++mt)
#pragma unroll
    for (int nt = 0; nt < 4; ++nt) {
      int row = bm * 128 + wm + mt * 16 + quad * 4;
      int col = bn * 128 + wn + nt * 16 + l15;
#pragma unroll
      for (int r = 0; r < 4; ++r)
        C[(size_t)(row + r) * N + col] = acc[mt][nt][r] * scale;
    }
}

// ---------------- normalize + pack -----------------------------------------
// qkv_cls[n][3072]: q=0..1023, k=1024..2047, v=2048..3071 (col = h*128+d)
// writes: Qc/Kc/Qr/Kr [h][n][128] f16 normalized; Vcat[n][1024] f16 normalized;
//         Vt [h][128][2048] f16 raw (transposed); x_ori -> out[n][1024+c] f32.
__global__ __launch_bounds__(256) void normpack_kernel(
    const float* __restrict__ qkv_cls, const float* __restrict__ qkv_reg,
    uint16_t* __restrict__ Qc, uint16_t* __restrict__ Kc,
    uint16_t* __restrict__ Qr, uint16_t* __restrict__ Kr,
    uint16_t* __restrict__ Vt, uint16_t* __restrict__ Vcat,
    float* __restrict__ out) {
  __shared__ uint16_t vtile[64 * 136];
  int nt = blockIdx.x, h = blockIdx.y;
  int tid = threadIdx.x;
  int rl = tid >> 2, part = tid & 3;
  int n = nt * 64 + rl;
  int dbase = part * 32;
  size_t dsti = ((size_t)h * 2048 + n) * 128 + dbase;

#pragma unroll
  for (int tz = 0; tz < 4; ++tz) {
    const float* s;
    uint16_t* dst;
    if (tz == 0)      { s = qkv_cls + (size_t)n * 3072 + h * 128 + dbase;        dst = Qc + dsti; }
    else if (tz == 1) { s = qkv_cls + (size_t)n * 3072 + 1024 + h * 128 + dbase; dst = Kc + dsti; }
    else if (tz == 2) { s = qkv_reg + (size_t)n * 2048 + h * 128 + dbase;        dst = Qr + dsti; }
    else              { s = qkv_reg + (size_t)n * 2048 + 1024 + h * 128 + dbase; dst = Kr + dsti; }
    float v[32];
    float ssum = 0.f;
#pragma unroll
    for (int j = 0; j < 32; j += 4) {
      float4 t4 = *(const float4*)(s + j);
      v[j] = t4.x; v[j + 1] = t4.y; v[j + 2] = t4.z; v[j + 3] = t4.w;
      ssum += t4.x * t4.x + t4.y * t4.y + t4.z * t4.z + t4.w * t4.w;
    }
    ssum += __shfl_xor(ssum, 1);
    ssum += __shfl_xor(ssum, 2);
    float rn = rsqrtf(ssum);
#pragma unroll
    for (int j = 0; j < 32; j += 8) {
      U16x8 o;
#pragma unroll
      for (int q = 0; q < 8; ++q) o.u[q] = f2h(v[j + q] * rn);
      *(i32x4*)(dst + j) = o.v;
    }
  }
  // v path
  {
    const float* s = qkv_cls + (size_t)n * 3072 + 2048 + h * 128 + dbase;
    float v[32];
    float ssum = 0.f;
#pragma unroll
    for (int j = 0; j < 32; j += 4) {
      float4 t4 = *(const float4*)(s + j);
      v[j] = t4.x; v[j + 1] = t4.y; v[j + 2] = t4.z; v[j + 3] = t4.w;
      ssum += t4.x * t4.x + t4.y * t4.y + t4.z * t4.z + t4.w * t4.w;
      *(float4*)(out + (size_t)n * 2048 + 1024 + h * 128 + dbase + j) = t4;
    }
    ssum += __shfl_xor(ssum, 1);
    ssum += __shfl_xor(ssum, 2);
    float rn = rsqrtf(ssum);
#pragma unroll
    for (int j = 0; j < 32; j += 8) {
      U16x8 o;
#pragma unroll
      for (int q = 0; q < 8; ++q) o.u[q] = f2h(v[j + q] * rn);
      *(i32x4*)(Vcat + (size_t)n * 1024 + h * 128 + dbase + j) = o.v;
    }
#pragma unroll
    for (int j = 0; j < 32; ++j) vtile[rl * 136 + dbase + j] = f2h(v[j]);
  }
  __syncthreads();
#pragma unroll
  for (int i = 0; i < 32; ++i) {
    int flat = i * 256 + tid;
    int d = flat >> 6, c = flat & 63;
    Vt[((size_t)h * 128 + d) * 2048 + nt * 64 + c] = vtile[c * 136 + d];
  }
}

// ---------------- fused flash attention (both paths) ------------------------
// grid 256: h = bx & 7, qtile = bx >> 3 (64 q-rows). Bk=64 chunks over m.
// stats layout: [ {Mc, Lc, Mr, Lr} ][h][2048]  (M in log2 domain)
__global__ __launch_bounds__(256, 1) void attn_kernel(
    const uint16_t* __restrict__ Qc, const uint16_t* __restrict__ Kc,
    const uint16_t* __restrict__ Qr, const uint16_t* __restrict__ Kr,
    const uint16_t* __restrict__ Vt,
    const float* __restrict__ cls_score, const float* __restrict__ fg_score,
    float* __restrict__ out, float* __restrict__ stats) {
  __shared__ __align__(16) uint16_t sKc[64 * 136];
  __shared__ __align__(16) uint16_t sKr[64 * 136];
  __shared__ __align__(16) uint16_t sVt[128 * 72];
  __shared__ __align__(16) uint16_t sP[4 * 16 * 72];

  int h = blockIdx.x & 7;
  int qt = blockIdx.x >> 3;
  int q0 = qt * 64;
  int tid = threadIdx.x, w = tid >> 6, lane = tid & 63;
  int quad = lane >> 4, l15 = lane & 15;
  int qbase = q0 + w * 16;
  uint16_t* Pb = sP + w * 1152;

  // Q fragments (held in registers for the whole block)
  f16x8 qcf[4], qrf[4];
  const uint16_t* qcp = Qc + ((size_t)h * 2048 + qbase + l15) * 128;
  const uint16_t* qrp = Qr + ((size_t)h * 2048 + qbase + l15) * 128;
#pragma unroll
  for (int ks = 0; ks < 4; ++ks) {
    qcf[ks] = ldfrag(qcp + ks * 32 + quad * 8);
    qrf[ks] = ldfrag(qrp + ks * 32 + quad * 8);
  }
  float sqc[4], sqr[4];
#pragma unroll
  for (int r = 0; r < 4; ++r) {
    sqc[r] = cls_score[qbase + quad * 4 + r] - 0.1f;
    sqr[r] = fg_score[qbase + quad * 4 + r] - 0.1f;
  }
  float Mc[4], Lc[4], Mr[4], Lr[4];
  f32x4 Oc[8], Or[8];
  f32x4 zero = {0.f, 0.f, 0.f, 0.f};
#pragma unroll
  for (int i = 0; i < 8; ++i) { Oc[i] = zero; Or[i] = zero; }
#pragma unroll
  for (int r = 0; r < 4; ++r) { Mc[r] = Mr[r] = -3.0e38f; Lc[r] = Lr[r] = 0.f; }

  for (int m0 = 0; m0 < 2048; m0 += 64) {
    __syncthreads();
    // stage K chunks: 64 rows x 128 halves (pad to 136)
#pragma unroll
    for (int t = 0; t < 4; ++t) {
      int r = w * 16 + t * 4 + (lane >> 4);
      int s = lane & 15;
      i32x4 vc = *(const i32x4*)(Kc + ((size_t)h * 2048 + m0 + r) * 128 + s * 8);
      i32x4 vr = *(const i32x4*)(Kr + ((size_t)h * 2048 + m0 + r) * 128 + s * 8);
      *(i32x4*)(sKc + r * 136 + s * 8) = vc;
      *(i32x4*)(sKr + r * 136 + s * 8) = vr;
    }
    // stage V^T chunk: 128 rows(d) x 64 halves (pad to 72)
#pragma unroll
    for (int t = 0; t < 4; ++t) {
      int d = w * 32 + t * 8 + (lane >> 3);
      int s = lane & 7;
      i32x4 vv = *(const i32x4*)(Vt + ((size_t)h * 128 + d) * 2048 + m0 + s * 8);
      *(i32x4*)(sVt + d * 72 + s * 8) = vv;
    }
    __syncthreads();

    auto process = [&](const f32x4* S, const float* score, const float* sq,
                       float* M, float* L, f32x4* O) {
      float l2[4][4];
#pragma unroll
      for (int mt = 0; mt < 4; ++mt) {
        float scm = score[m0 + mt * 16 + l15];
        float sc2 = scm * (25.0f * K2E);
#pragma unroll
        for (int r = 0; r < 4; ++r) {
          float msk = (scm > sq[r]) ? 1.0f : 0.0f;
          l2[mt][r] = S[mt][r] * sc2 * msk;
        }
      }
      float Mnew[4], alpha[4];
#pragma unroll
      for (int r = 0; r < 4; ++r) {
        float v = fmaxf(fmaxf(l2[0][r], l2[1][r]), fmaxf(l2[2][r], l2[3][r]));
        v = fmaxf(v, __shfl_xor(v, 1));
        v = fmaxf(v, __shfl_xor(v, 2));
        v = fmaxf(v, __shfl_xor(v, 4));
        v = fmaxf(v, __shfl_xor(v, 8));
        Mnew[r] = fmaxf(M[r], v);
        alpha[r] = __builtin_amdgcn_exp2f(M[r] - Mnew[r]);
        M[r] = Mnew[r];
      }
#pragma unroll
      for (int r = 0; r < 4; ++r) {
        float s = 0.f;
#pragma unroll
        for (int mt = 0; mt < 4; ++mt) {
          float p = __builtin_amdgcn_exp2f(l2[mt][r] - Mnew[r]);
          l2[mt][r] = p;
          s += p;
        }
        s += __shfl_xor(s, 1);
        s += __shfl_xor(s, 2);
        s += __shfl_xor(s, 4);
        s += __shfl_xor(s, 8);
        L[r] = L[r] * alpha[r] + s;
      }
#pragma unroll
      for (int dt = 0; dt < 8; ++dt)
#pragma unroll
        for (int r = 0; r < 4; ++r) O[dt][r] *= alpha[r];
      // P -> LDS (per-wave region), C-layout row=quad*4+r, col=mt*16+l15
#pragma unroll
      for (int mt = 0; mt < 4; ++mt)
#pragma unroll
        for (int r = 0; r < 4; ++r)
          Pb[(quad * 4 + r) * 72 + mt * 16 + l15] = f2h(l2[mt][r]);
      // PV
#pragma unroll
      for (int ks2 = 0; ks2 < 2; ++ks2) {
        f16x8 a = ldfrag(Pb + l15 * 72 + ks2 * 32 + quad * 8);
#pragma unroll
        for (int dt = 0; dt < 8; ++dt) {
          f16x8 b = ldfrag(sVt + (dt * 16 + l15) * 72 + ks2 * 32 + quad * 8);
          O[dt] = mfma16(a, b, O[dt]);
        }
      }
    };

    // cls path
    {
      f32x4 S[4];
#pragma unroll
      for (int mt = 0; mt < 4; ++mt) S[mt] = zero;
#pragma unroll
      for (int ks = 0; ks < 4; ++ks)
#pragma unroll
        for (int mt = 0; mt < 4; ++mt) {
          f16x8 b = ldfrag(sKc + (mt * 16 + l15) * 136 + ks * 32 + quad * 8);
          S[mt] = mfma16(qcf[ks], b, S[mt]);
        }
      process(S, cls_score, sqc, Mc, Lc, Oc);
    }
    // reg path
    {
      f32x4 S[4];
#pragma unroll
      for (int mt = 0; mt < 4; ++mt) S[mt] = zero;
#pragma unroll
      for (int ks = 0; ks < 4; ++ks)
#pragma unroll
        for (int mt = 0; mt < 4; ++mt) {
          f16x8 b = ldfrag(sKr + (mt * 16 + l15) * 136 + ks * 32 + quad * 8);
          S[mt] = mfma16(qrf[ks], b, S[mt]);
        }
      process(S, fg_score, sqr, Mr, Lr, Or);
    }
  }

  float rLc[4], rLr[4];
#pragma unroll
  for (int r = 0; r < 4; ++r) { rLc[r] = 1.0f / Lc[r]; rLr[r] = 1.0f / Lr[r]; }
#pragma unroll
  for (int dt = 0; dt < 8; ++dt)
#pragma unroll
    for (int r = 0; r < 4; ++r) {
      int qrow = qbase + quad * 4 + r;
      int col = h * 128 + dt * 16 + l15;
      out[(size_t)qrow * 2048 + col] =
          0.5f * (Oc[dt][r] * rLc[r] + Or[dt][r] * rLr[r]);
    }
  if (l15 == 0) {
#pragma unroll
    for (int r = 0; r < 4; ++r) {
      int qrow = qbase + quad * 4 + r;
      stats[((size_t)0 * 8 + h) * 2048 + qrow] = Mc[r];
      stats[((size_t)1 * 8 + h) * 2048 + qrow] = Lc[r];
      stats[((size_t)2 * 8 + h) * 2048 + qrow] = Mr[r];
      stats[((size_t)3 * 8 + h) * 2048 + qrow] = Lr[r];
    }
  }
}

// ---------------- sim_round2: masked-restricted softmax ---------------------
__global__ __launch_bounds__(256) void sim_kernel(
    const float* __restrict__ raw_mean,
    const uint16_t* __restrict__ Qc, const uint16_t* __restrict__ Kc,
    const uint16_t* __restrict__ Qr, const uint16_t* __restrict__ Kr,
    const float* __restrict__ cls_score, const float* __restrict__ fg_score,
    const float* __restrict__ stats, float* __restrict__ simout) {
  int n = blockIdx.x;
  int tid = threadIdx.x;
  __shared__ float red[4];
  __shared__ float s_inv;
  float e[8];
  float psum = 0.f;
  float cs_n = cls_score[n] - 0.1f, fs_n = fg_score[n] - 0.1f;
#pragma unroll
  for (int i = 0; i < 8; ++i) {
    int m = i * 256 + tid;
    float rm = raw_mean[(size_t)n * 2048 + m];
    float val = 0.f;
    if (rm > 0.75f) {
      float s = 0.f;
      float c2 = 25.0f * K2E * cls_score[m];
      float r2 = 25.0f * K2E * fg_score[m];
      float mc = (cls_score[m] > cs_n) ? 1.f : 0.f;
      float mr = (fg_score[m] > fs_n) ? 1.f : 0.f;
      for (int hh = 0; hh < 8; ++hh) {
        const uint16_t* qc = Qc + ((size_t)hh * 2048 + n) * 128;
        const uint16_t* kc = Kc + ((size_t)hh * 2048 + m) * 128;
        const uint16_t* qr = Qr + ((size_t)hh * 2048 + n) * 128;
        const uint16_t* kr = Kr + ((size_t)hh * 2048 + m) * 128;
        float dc = 0.f, dr = 0.f;
        for (int d = 0; d < 128; ++d) {
          dc += h2f(qc[d]) * h2f(kc[d]);
          dr += h2f(qr[d]) * h2f(kr[d]);
        }
        float lc = dc * c2 * mc;
        float lr = dr * r2 * mr;
        float ac = __builtin_amdgcn_exp2f(lc - stats[((size_t)0 * 8 + hh) * 2048 + n]) /
                   stats[((size_t)1 * 8 + hh) * 2048 + n];
        float ar = __builtin_amdgcn_exp2f(lr - stats[((size_t)2 * 8 + hh) * 2048 + n]) /
                   stats[((size_t)3 * 8 + hh) * 2048 + n];
        s += ac + ar;
      }
      s *= (1.0f / 16.0f);
      val = __builtin_amdgcn_exp2f(s * K2E);  // e^s
    }
    e[i] = val;
    psum += val;
  }
  for (int off = 1; off < 64; off <<= 1) psum += __shfl_xor(psum, off);
  if ((tid & 63) == 0) red[tid >> 6] = psum;
  __syncthreads();
  if (tid == 0) s_inv = 1.0f / (red[0] + red[1] + red[2] + red[3]);
  __syncthreads();
  float inv = s_inv;
#pragma unroll
  for (int i = 0; i < 8; ++i)
    simout[(size_t)n * 2048 + i * 256 + tid] = e[i] * inv;
}

// ---------------- host launch ------------------------------------------------
extern "C" void kernel_launch(void* const* d_in, const int* in_sizes, int n_in,
                              void* d_out, int out_size, void* d_ws, size_t ws_size,
                              hipStream_t stream) {
  const float* x_cls = (const float*)d_in[0];
  const float* x_reg = (const float*)d_in[1];
  const float* cls_score = (const float*)d_in[2];
  const float* fg_score = (const float*)d_in[3];
  const float* W_cls = (const float*)d_in[4];
  const float* W_reg = (const float*)d_in[5];
  float* out = (float*)d_out;
  char* ws = (char*)d_ws;

  const size_t OFF_XC   = 0;
  const size_t OFF_XR   = OFF_XC + 4194304;
  const size_t OFF_WTC  = OFF_XR + 4194304;
  const size_t OFF_WTR  = OFF_WTC + 6291456;
  const size_t OFF_QC   = OFF_WTR + 4194304;
  const size_t OFF_KC   = OFF_QC + 4194304;
  const size_t OFF_QR   = OFF_KC + 4194304;
  const size_t OFF_KR   = OFF_QR + 4194304;
  const size_t OFF_VT   = OFF_KR + 4194304;
  const size_t OFF_VCAT = OFF_VT + 4194304;
  const size_t OFF_STAT = OFF_VCAT + 4194304;
  const size_t OFF_QKVC = OFF_STAT + 262144;        // 25,165,824 bytes
  const size_t OFF_QKVR = OFF_QKVC + 25165824;      // 16,777,216 bytes
  // raw_mean aliases the (dead-by-then) qkv_cls region.
  const size_t OFF_RAW  = OFF_QKVC;

  uint16_t* xc_b = (uint16_t*)(ws + OFF_XC);
  uint16_t* xr_b = (uint16_t*)(ws + OFF_XR);
  uint16_t* Wtc  = (uint16_t*)(ws + OFF_WTC);
  uint16_t* Wtr  = (uint16_t*)(ws + OFF_WTR);
  uint16_t* Qc   = (uint16_t*)(ws + OFF_QC);
  uint16_t* Kc   = (uint16_t*)(ws + OFF_KC);
  uint16_t* Qr   = (uint16_t*)(ws + OFF_QR);
  uint16_t* Kr   = (uint16_t*)(ws + OFF_KR);
  uint16_t* Vt   = (uint16_t*)(ws + OFF_VT);
  uint16_t* Vcat = (uint16_t*)(ws + OFF_VCAT);
  float* stats   = (float*)(ws + OFF_STAT);
  float* qkvc    = (float*)(ws + OFF_QKVC);
  float* qkvr    = (float*)(ws + OFF_QKVR);
  float* rawm    = (float*)(ws + OFF_RAW);

  cast_f16_kernel<<<1024, 256, 0, stream>>>(x_cls, xc_b, 262144);
  cast_f16_kernel<<<1024, 256, 0, stream>>>(x_reg, xr_b, 262144);
  transpose_cast_kernel<<<dim3(16, 48), 256, 0, stream>>>(W_cls, Wtc, 3072);
  transpose_cast_kernel<<<dim3(16, 32), 256, 0, stream>>>(W_reg, Wtr, 3072);
  gemm_bt_kernel<<<dim3(16, 24), 256, 0, stream>>>(xc_b, Wtc, qkvc, 3072, 1024, 1.0f);
  gemm_bt_kernel<<<dim3(16, 16), 256, 0, stream>>>(xr_b, Wtr, qkvr, 2048, 1024, 1.0f);
  normpack_kernel<<<dim3(32, 8), 256, 0, stream>>>(qkvc, qkvr, Qc, Kc, Qr, Kr, Vt, Vcat, out);
  gemm_bt_kernel<<<dim3(16, 16), 256, 0, stream>>>(Vcat, Vcat, rawm, 2048, 1024, 0.125f);
  attn_kernel<<<256, 256, 0, stream>>>(Qc, Kc, Qr, Kr, Vt, cls_score, fg_score, out, stats);
  sim_kernel<<<2048, 256, 0, stream>>>(rawm, Qc, Kc, Qr, Kr, cls_score, fg_score,
                                       stats, out + 4194304);
}

// Round 2
// 355.732 us; speedup vs baseline: 1.0382x; 1.0382x over previous
//
#include <hip/hip_runtime.h>
#include <stdint.h>
#include <stddef.h>

#define DEV __device__ __forceinline__

typedef _Float16 f16x8 __attribute__((ext_vector_type(8)));
typedef float    f32x4 __attribute__((ext_vector_type(4)));
typedef int      i32x4 __attribute__((ext_vector_type(4)));

#define K2E 1.44269504088896340736f

DEV uint16_t f2h(float f) {
  _Float16 h = (_Float16)f;
  return __builtin_bit_cast(uint16_t, h);
}
DEV float h2f(uint16_t u) {
  return (float)__builtin_bit_cast(_Float16, u);
}
DEV f16x8 ldfrag(const uint16_t* p) {
  i32x4 v = *(const i32x4*)p;
  return __builtin_bit_cast(f16x8, v);
}
DEV f32x4 mfma16(f16x8 a, f16x8 b, f32x4 c) {
  return __builtin_amdgcn_mfma_f32_16x16x32_f16(a, b, c, 0, 0, 0);
}

union U16x8 { uint16_t u[8]; i32x4 v; };

// ---------------- cast f32 -> f16 (8 elems/thread) ----------------
__global__ __launch_bounds__(256) void cast_f16_kernel(
    const float* __restrict__ in, uint16_t* __restrict__ outp, int n8) {
  int i = blockIdx.x * 256 + threadIdx.x;
  if (i >= n8) return;
  float4 a = *(const float4*)(in + (size_t)i * 8);
  float4 b = *(const float4*)(in + (size_t)i * 8 + 4);
  U16x8 r;
  r.u[0] = f2h(a.x); r.u[1] = f2h(a.y); r.u[2] = f2h(a.z); r.u[3] = f2h(a.w);
  r.u[4] = f2h(b.x); r.u[5] = f2h(b.y); r.u[6] = f2h(b.z); r.u[7] = f2h(b.w);
  *(i32x4*)(outp + (size_t)i * 8) = r.v;
}

// ---------------- transpose + cast: W[1024][ldw] f32 -> Wt[n][1024] f16 ----
__global__ __launch_bounds__(256) void transpose_cast_kernel(
    const float* __restrict__ W, uint16_t* __restrict__ Wt, int ldw) {
  __shared__ float tile[64][65];
  int k0 = blockIdx.x * 64;
  int n0 = blockIdx.y * 64;
  int tid = threadIdx.x;
#pragma unroll
  for (int i = 0; i < 16; ++i) {
    int flat = i * 256 + tid;
    int r = flat >> 6, c = flat & 63;
    tile[r][c] = W[(size_t)(k0 + r) * ldw + n0 + c];
  }
  __syncthreads();
#pragma unroll
  for (int i = 0; i < 16; ++i) {
    int flat = i * 256 + tid;
    int r = flat >> 6, c = flat & 63;
    Wt[(size_t)(n0 + r) * 1024 + k0 + c] = f2h(tile[c][r]);
  }
}

// ---------------- GEMM: C[M,N] = A[M,K] @ Bt[N,K]^T  (f16 in, f32 out) -----
// 128x128 tile, BK=64, padded LDS (stride 72 halves) => conflict-free b128.
__global__ __launch_bounds__(256, 2) void gemm_bt_kernel(
    const uint16_t* __restrict__ A, const uint16_t* __restrict__ Bt,
    float* __restrict__ C, int N, int K, float scale) {
  __shared__ __align__(16) uint16_t As[128 * 72];
  __shared__ __align__(16) uint16_t Bs[128 * 72];
  int tid = threadIdx.x;
  int w = tid >> 6, lane = tid & 63, quad = lane >> 4, l15 = lane & 15;
  int wm = (w >> 1) * 64, wn = (w & 1) * 64;
  int bm = blockIdx.x, bn = blockIdx.y;
  const uint16_t* Arow = A + (size_t)(bm * 128) * K;
  const uint16_t* Brow = Bt + (size_t)(bn * 128) * K;
  f32x4 acc[4][4];
  f32x4 zero = {0.f, 0.f, 0.f, 0.f};
#pragma unroll
  for (int i = 0; i < 4; ++i)
#pragma unroll
    for (int j = 0; j < 4; ++j) acc[i][j] = zero;
  int ss = lane & 7;
  for (int k0 = 0; k0 < K; k0 += 64) {
    __syncthreads();
#pragma unroll
    for (int t = 0; t < 4; ++t) {
      int r = w * 32 + t * 8 + (lane >> 3);
      i32x4 va = *(const i32x4*)(Arow + (size_t)r * K + k0 + ss * 8);
      i32x4 vb = *(const i32x4*)(Brow + (size_t)r * K + k0 + ss * 8);
      *(i32x4*)(As + r * 72 + ss * 8) = va;
      *(i32x4*)(Bs + r * 72 + ss * 8) = vb;
    }
    __syncthreads();
#pragma unroll
    for (int ks = 0; ks < 2; ++ks) {
      f16x8 af[4], bf[4];
#pragma unroll
      for (int mt = 0; mt < 4; ++mt)
        af[mt] = ldfrag(As + (wm + mt * 16 + l15) * 72 + ks * 32 + quad * 8);
#pragma unroll
      for (int nt = 0; nt < 4; ++nt)
        bf[nt] = ldfrag(Bs + (wn + nt * 16 + l15) * 72 + ks * 32 + quad * 8);
#pragma unroll
      for (int mt = 0; mt < 4; ++mt)
#pragma unroll
        for (int nt = 0; nt < 4; ++nt)
          acc[mt][nt] = mfma16(af[mt], bf[nt], acc[mt][nt]);
    }
  }
#pragma unroll
  for (int mt = 0; mt < 4; ++mt)
#pragma unroll
    for (int nt = 0; nt < 4; ++nt) {
      int row = bm * 128 + wm + mt * 16 + quad * 4;
      int col = bn * 128 + wn + nt * 16 + l15;
#pragma unroll
      for (int r = 0; r < 4; ++r)
        C[(size_t)(row + r) * N + col] = acc[mt][nt][r] * scale;
    }
}

// ---------------- normalize + pack -----------------------------------------
__global__ __launch_bounds__(256) void normpack_kernel(
    const float* __restrict__ qkv_cls, const float* __restrict__ qkv_reg,
    uint16_t* __restrict__ Qc, uint16_t* __restrict__ Kc,
    uint16_t* __restrict__ Qr, uint16_t* __restrict__ Kr,
    uint16_t* __restrict__ Vt, uint16_t* __restrict__ Vcat,
    float* __restrict__ out) {
  __shared__ uint16_t vtile[64 * 136];
  int nt = blockIdx.x, h = blockIdx.y;
  int tid = threadIdx.x;
  int rl = tid >> 2, part = tid & 3;
  int n = nt * 64 + rl;
  int dbase = part * 32;
  size_t dsti = ((size_t)h * 2048 + n) * 128 + dbase;

#pragma unroll
  for (int tz = 0; tz < 4; ++tz) {
    const float* s;
    uint16_t* dst;
    if (tz == 0)      { s = qkv_cls + (size_t)n * 3072 + h * 128 + dbase;        dst = Qc + dsti; }
    else if (tz == 1) { s = qkv_cls + (size_t)n * 3072 + 1024 + h * 128 + dbase; dst = Kc + dsti; }
    else if (tz == 2) { s = qkv_reg + (size_t)n * 2048 + h * 128 + dbase;        dst = Qr + dsti; }
    else              { s = qkv_reg + (size_t)n * 2048 + 1024 + h * 128 + dbase; dst = Kr + dsti; }
    float v[32];
    float ssum = 0.f;
#pragma unroll
    for (int j = 0; j < 32; j += 4) {
      float4 t4 = *(const float4*)(s + j);
      v[j] = t4.x; v[j + 1] = t4.y; v[j + 2] = t4.z; v[j + 3] = t4.w;
      ssum += t4.x * t4.x + t4.y * t4.y + t4.z * t4.z + t4.w * t4.w;
    }
    ssum += __shfl_xor(ssum, 1);
    ssum += __shfl_xor(ssum, 2);
    float rn = rsqrtf(ssum);
#pragma unroll
    for (int j = 0; j < 32; j += 8) {
      U16x8 o;
#pragma unroll
      for (int q = 0; q < 8; ++q) o.u[q] = f2h(v[j + q] * rn);
      *(i32x4*)(dst + j) = o.v;
    }
  }
  // v path
  {
    const float* s = qkv_cls + (size_t)n * 3072 + 2048 + h * 128 + dbase;
    float v[32];
    float ssum = 0.f;
#pragma unroll
    for (int j = 0; j < 32; j += 4) {
      float4 t4 = *(const float4*)(s + j);
      v[j] = t4.x; v[j + 1] = t4.y; v[j + 2] = t4.z; v[j + 3] = t4.w;
      ssum += t4.x * t4.x + t4.y * t4.y + t4.z * t4.z + t4.w * t4.w;
      *(float4*)(out + (size_t)n * 2048 + 1024 + h * 128 + dbase + j) = t4;
    }
    ssum += __shfl_xor(ssum, 1);
    ssum += __shfl_xor(ssum, 2);
    float rn = rsqrtf(ssum);
#pragma unroll
    for (int j = 0; j < 32; j += 8) {
      U16x8 o;
#pragma unroll
      for (int q = 0; q < 8; ++q) o.u[q] = f2h(v[j + q] * rn);
      *(i32x4*)(Vcat + (size_t)n * 1024 + h * 128 + dbase + j) = o.v;
    }
#pragma unroll
    for (int j = 0; j < 32; ++j) vtile[rl * 136 + dbase + j] = f2h(v[j]);
  }
  __syncthreads();
#pragma unroll
  for (int i = 0; i < 32; ++i) {
    int flat = i * 256 + tid;
    int d = flat >> 6, c = flat & 63;
    Vt[((size_t)h * 128 + d) * 2048 + nt * 64 + c] = vtile[c * 136 + d];
  }
}

// ---------------- fused flash attention (both paths) ------------------------
// grid 512: h = bx & 7, qtile = bx >> 3 (32 q-rows). Bk=64 chunks over m.
// Wave w: path p = w>>1 (0=cls,1=reg), rowgroup g = w&1 (16 rows each).
// 2 blocks/CU (LDS 62.5KB). stats layout: [ {Mc, Lc, Mr, Lr} ][h][2048].
__global__ __launch_bounds__(256, 2) void attn_kernel(
    const uint16_t* __restrict__ Qc, const uint16_t* __restrict__ Kc,
    const uint16_t* __restrict__ Qr, const uint16_t* __restrict__ Kr,
    const uint16_t* __restrict__ Vt,
    const float* __restrict__ cls_score, const float* __restrict__ fg_score,
    float* __restrict__ out, float* __restrict__ stats) {
  __shared__ __align__(16) uint16_t sKc[64 * 136];
  __shared__ __align__(16) uint16_t sKr[64 * 136];
  __shared__ __align__(16) uint16_t sVt[128 * 72];
  __shared__ __align__(16) uint16_t sP[4 * 16 * 72];

  int h = blockIdx.x & 7;
  int qt = blockIdx.x >> 3;
  int tid = threadIdx.x, w = tid >> 6, lane = tid & 63;
  int quad = lane >> 4, l15 = lane & 15;
  int p = w >> 1;       // 0 = cls, 1 = reg
  int g = w & 1;        // rowgroup within the 32-row q-tile
  int qbase = qt * 32 + g * 16;
  uint16_t* Pb = sP + w * 1152;

  const uint16_t* Qp = p ? Qr : Qc;
  const float* score = p ? fg_score : cls_score;

  // Q fragments (one path per wave, held for the whole block)
  f16x8 qf[4];
  const uint16_t* qp = Qp + ((size_t)h * 2048 + qbase + l15) * 128;
#pragma unroll
  for (int ks = 0; ks < 4; ++ks) qf[ks] = ldfrag(qp + ks * 32 + quad * 8);

  float sq[4];
#pragma unroll
  for (int r = 0; r < 4; ++r) sq[r] = score[qbase + quad * 4 + r] - 0.1f;

  float M[4], L[4];
  f32x4 O[8];
  f32x4 zero = {0.f, 0.f, 0.f, 0.f};
#pragma unroll
  for (int i = 0; i < 8; ++i) O[i] = zero;
#pragma unroll
  for (int r = 0; r < 4; ++r) { M[r] = -3.0e38f; L[r] = 0.f; }

  for (int m0 = 0; m0 < 2048; m0 += 64) {
    __syncthreads();
    // stage K chunks (both paths, all 4 waves): 64 rows x 128 halves (pad 136)
#pragma unroll
    for (int t = 0; t < 4; ++t) {
      int r = w * 16 + t * 4 + (lane >> 4);
      int s = lane & 15;
      i32x4 vc = *(const i32x4*)(Kc + ((size_t)h * 2048 + m0 + r) * 128 + s * 8);
      i32x4 vr = *(const i32x4*)(Kr + ((size_t)h * 2048 + m0 + r) * 128 + s * 8);
      *(i32x4*)(sKc + r * 136 + s * 8) = vc;
      *(i32x4*)(sKr + r * 136 + s * 8) = vr;
    }
    // stage V^T chunk: 128 rows(d) x 64 halves (pad 72)
#pragma unroll
    for (int t = 0; t < 4; ++t) {
      int d = w * 32 + t * 8 + (lane >> 3);
      int s = lane & 7;
      i32x4 vv = *(const i32x4*)(Vt + ((size_t)h * 128 + d) * 2048 + m0 + s * 8);
      *(i32x4*)(sVt + d * 72 + s * 8) = vv;
    }
    __syncthreads();

    const uint16_t* sK = p ? sKr : sKc;
    // QK^T: 16 q-rows x 64 m-cols
    f32x4 S[4];
#pragma unroll
    for (int mt = 0; mt < 4; ++mt) S[mt] = zero;
#pragma unroll
    for (int ks = 0; ks < 4; ++ks)
#pragma unroll
      for (int mt = 0; mt < 4; ++mt) {
        f16x8 b = ldfrag(sK + (mt * 16 + l15) * 136 + ks * 32 + quad * 8);
        S[mt] = mfma16(qf[ks], b, S[mt]);
      }

    // online softmax
    float l2[4][4];
#pragma unroll
    for (int mt = 0; mt < 4; ++mt) {
      float scm = score[m0 + mt * 16 + l15];
      float sc2 = scm * (25.0f * K2E);
#pragma unroll
      for (int r = 0; r < 4; ++r) {
        float msk = (scm > sq[r]) ? 1.0f : 0.0f;
        l2[mt][r] = S[mt][r] * sc2 * msk;
      }
    }
    float Mnew[4], alpha[4];
#pragma unroll
    for (int r = 0; r < 4; ++r) {
      float v = fmaxf(fmaxf(l2[0][r], l2[1][r]), fmaxf(l2[2][r], l2[3][r]));
      v = fmaxf(v, __shfl_xor(v, 1));
      v = fmaxf(v, __shfl_xor(v, 2));
      v = fmaxf(v, __shfl_xor(v, 4));
      v = fmaxf(v, __shfl_xor(v, 8));
      Mnew[r] = fmaxf(M[r], v);
      alpha[r] = __builtin_amdgcn_exp2f(M[r] - Mnew[r]);
      M[r] = Mnew[r];
    }
#pragma unroll
    for (int r = 0; r < 4; ++r) {
      float s = 0.f;
#pragma unroll
      for (int mt = 0; mt < 4; ++mt) {
        float pe = __builtin_amdgcn_exp2f(l2[mt][r] - Mnew[r]);
        l2[mt][r] = pe;
        s += pe;
      }
      s += __shfl_xor(s, 1);
      s += __shfl_xor(s, 2);
      s += __shfl_xor(s, 4);
      s += __shfl_xor(s, 8);
      L[r] = L[r] * alpha[r] + s;
    }
#pragma unroll
    for (int dt = 0; dt < 8; ++dt)
#pragma unroll
      for (int r = 0; r < 4; ++r) O[dt][r] *= alpha[r];
    // P -> LDS (per-wave region), C-layout row=quad*4+r, col=mt*16+l15
#pragma unroll
    for (int mt = 0; mt < 4; ++mt)
#pragma unroll
      for (int r = 0; r < 4; ++r)
        Pb[(quad * 4 + r) * 72 + mt * 16 + l15] = f2h(l2[mt][r]);
    // PV
#pragma unroll
    for (int ks2 = 0; ks2 < 2; ++ks2) {
      f16x8 a = ldfrag(Pb + l15 * 72 + ks2 * 32 + quad * 8);
#pragma unroll
      for (int dt = 0; dt < 8; ++dt) {
        f16x8 b = ldfrag(sVt + (dt * 16 + l15) * 72 + ks2 * 32 + quad * 8);
        O[dt] = mfma16(a, b, O[dt]);
      }
    }
  }

  // epilogue: combine cls (waves 0,1) + reg (waves 2,3) through LDS
  float invL[4];
#pragma unroll
  for (int r = 0; r < 4; ++r) invL[r] = 0.5f / L[r];

  __syncthreads();
  if (p == 1) {
    float* comb = (float*)(g ? sKr : sKc);
#pragma unroll
    for (int dt = 0; dt < 8; ++dt)
#pragma unroll
      for (int r = 0; r < 4; ++r)
        comb[(quad * 4 + r) * 132 + dt * 16 + l15] = O[dt][r] * invL[r];
  }
  __syncthreads();
  if (p == 0) {
    const float* comb = (const float*)(g ? sKr : sKc);
#pragma unroll
    for (int dt = 0; dt < 8; ++dt)
#pragma unroll
      for (int r = 0; r < 4; ++r) {
        int qrow = qbase + quad * 4 + r;
        int col = h * 128 + dt * 16 + l15;
        out[(size_t)qrow * 2048 + col] =
            O[dt][r] * invL[r] + comb[(quad * 4 + r) * 132 + dt * 16 + l15];
      }
  }
  if (l15 == 0) {
#pragma unroll
    for (int r = 0; r < 4; ++r) {
      int qrow = qbase + quad * 4 + r;
      stats[((size_t)(p * 2 + 0) * 8 + h) * 2048 + qrow] = M[r];
      stats[((size_t)(p * 2 + 1) * 8 + h) * 2048 + qrow] = L[r];
    }
  }
}

// ---------------- sim_round2: masked-restricted softmax ---------------------
__global__ __launch_bounds__(256) void sim_kernel(
    const float* __restrict__ raw_mean,
    const uint16_t* __restrict__ Qc, const uint16_t* __restrict__ Kc,
    const uint16_t* __restrict__ Qr, const uint16_t* __restrict__ Kr,
    const float* __restrict__ cls_score, const float* __restrict__ fg_score,
    const float* __restrict__ stats, float* __restrict__ simout) {
  int n = blockIdx.x;
  int tid = threadIdx.x;
  __shared__ float red[4];
  __shared__ float s_inv;
  float e[8];
  float psum = 0.f;
  float cs_n = cls_score[n] - 0.1f, fs_n = fg_score[n] - 0.1f;
#pragma unroll
  for (int i = 0; i < 8; ++i) {
    int m = i * 256 + tid;
    float rm = raw_mean[(size_t)n * 2048 + m];
    float val = 0.f;
    if (rm > 0.75f) {
      float s = 0.f;
      float c2 = 25.0f * K2E * cls_score[m];
      float r2 = 25.0f * K2E * fg_score[m];
      float mc = (cls_score[m] > cs_n) ? 1.f : 0.f;
      float mr = (fg_score[m] > fs_n) ? 1.f : 0.f;
      for (int hh = 0; hh < 8; ++hh) {
        const uint16_t* qc = Qc + ((size_t)hh * 2048 + n) * 128;
        const uint16_t* kc = Kc + ((size_t)hh * 2048 + m) * 128;
        const uint16_t* qr = Qr + ((size_t)hh * 2048 + n) * 128;
        const uint16_t* kr = Kr + ((size_t)hh * 2048 + m) * 128;
        float dc = 0.f, dr = 0.f;
        for (int d = 0; d < 128; ++d) {
          dc += h2f(qc[d]) * h2f(kc[d]);
          dr += h2f(qr[d]) * h2f(kr[d]);
        }
        float lc = dc * c2 * mc;
        float lr = dr * r2 * mr;
        float ac = __builtin_amdgcn_exp2f(lc - stats[((size_t)0 * 8 + hh) * 2048 + n]) /
                   stats[((size_t)1 * 8 + hh) * 2048 + n];
        float ar = __builtin_amdgcn_exp2f(lr - stats[((size_t)2 * 8 + hh) * 2048 + n]) /
                   stats[((size_t)3 * 8 + hh) * 2048 + n];
        s += ac + ar;
      }
      s *= (1.0f / 16.0f);
      val = __builtin_amdgcn_exp2f(s * K2E);  // e^s
    }
    e[i] = val;
    psum += val;
  }
  for (int off = 1; off < 64; off <<= 1) psum += __shfl_xor(psum, off);
  if ((tid & 63) == 0) red[tid >> 6] = psum;
  __syncthreads();
  if (tid == 0) s_inv = 1.0f / (red[0] + red[1] + red[2] + red[3]);
  __syncthreads();
  float inv = s_inv;
#pragma unroll
  for (int i = 0; i < 8; ++i)
    simout[(size_t)n * 2048 + i * 256 + tid] = e[i] * inv;
}

// ---------------- host launch ------------------------------------------------
extern "C" void kernel_launch(void* const* d_in, const int* in_sizes, int n_in,
                              void* d_out, int out_size, void* d_ws, size_t ws_size,
                              hipStream_t stream) {
  const float* x_cls = (const float*)d_in[0];
  const float* x_reg = (const float*)d_in[1];
  const float* cls_score = (const float*)d_in[2];
  const float* fg_score = (const float*)d_in[3];
  const float* W_cls = (const float*)d_in[4];
  const float* W_reg = (const float*)d_in[5];
  float* out = (float*)d_out;
  char* ws = (char*)d_ws;

  const size_t OFF_XC   = 0;
  const size_t OFF_XR   = OFF_XC + 4194304;
  const size_t OFF_WTC  = OFF_XR + 4194304;
  const size_t OFF_WTR  = OFF_WTC + 6291456;
  const size_t OFF_QC   = OFF_WTR + 4194304;
  const size_t OFF_KC   = OFF_QC + 4194304;
  const size_t OFF_QR   = OFF_KC + 4194304;
  const size_t OFF_KR   = OFF_QR + 4194304;
  const size_t OFF_VT   = OFF_KR + 4194304;
  const size_t OFF_VCAT = OFF_VT + 4194304;
  const size_t OFF_STAT = OFF_VCAT + 4194304;
  const size_t OFF_QKVC = OFF_STAT + 262144;
  const size_t OFF_QKVR = OFF_QKVC + 25165824;
  const size_t OFF_RAW  = OFF_QKVC;  // raw_mean aliases dead qkv_cls

  uint16_t* xc_b = (uint16_t*)(ws + OFF_XC);
  uint16_t* xr_b = (uint16_t*)(ws + OFF_XR);
  uint16_t* Wtc  = (uint16_t*)(ws + OFF_WTC);
  uint16_t* Wtr  = (uint16_t*)(ws + OFF_WTR);
  uint16_t* Qc   = (uint16_t*)(ws + OFF_QC);
  uint16_t* Kc   = (uint16_t*)(ws + OFF_KC);
  uint16_t* Qr   = (uint16_t*)(ws + OFF_QR);
  uint16_t* Kr   = (uint16_t*)(ws + OFF_KR);
  uint16_t* Vt   = (uint16_t*)(ws + OFF_VT);
  uint16_t* Vcat = (uint16_t*)(ws + OFF_VCAT);
  float* stats   = (float*)(ws + OFF_STAT);
  float* qkvc    = (float*)(ws + OFF_QKVC);
  float* qkvr    = (float*)(ws + OFF_QKVR);
  float* rawm    = (float*)(ws + OFF_RAW);

  cast_f16_kernel<<<1024, 256, 0, stream>>>(x_cls, xc_b, 262144);
  cast_f16_kernel<<<1024, 256, 0, stream>>>(x_reg, xr_b, 262144);
  transpose_cast_kernel<<<dim3(16, 48), 256, 0, stream>>>(W_cls, Wtc, 3072);
  transpose_cast_kernel<<<dim3(16, 32), 256, 0, stream>>>(W_reg, Wtr, 3072);
  gemm_bt_kernel<<<dim3(16, 24), 256, 0, stream>>>(xc_b, Wtc, qkvc, 3072, 1024, 1.0f);
  gemm_bt_kernel<<<dim3(16, 16), 256, 0, stream>>>(xr_b, Wtr, qkvr, 2048, 1024, 1.0f);
  normpack_kernel<<<dim3(32, 8), 256, 0, stream>>>(qkvc, qkvr, Qc, Kc, Qr, Kr, Vt, Vcat, out);
  gemm_bt_kernel<<<dim3(16, 16), 256, 0, stream>>>(Vcat, Vcat, rawm, 2048, 1024, 0.125f);
  attn_kernel<<<512, 256, 0, stream>>>(Qc, Kc, Qr, Kr, Vt, cls_score, fg_score, out, stats);
  sim_kernel<<<2048, 256, 0, stream>>>(rawm, Qc, Kc, Qr, Kr, cls_score, fg_score,
                                       stats, out + 4194304);
}